// Round 1
// 309.712 us; speedup vs baseline: 1.3163x; 1.3163x over previous
//
#include <hip/hip_runtime.h>
#include <math.h>

// Problem constants
// O=64, I=64, K=3, NH=64, M=32, TEMP=0.5, F_GAMMA=0.3, PAD=1, B=64, T=8192
#define TT 128
#define TP 72   // xs[t][i] row pitch in bf16: 144 B = 9*16 -> every row b128-aligned

typedef short bf16x8 __attribute__((ext_vector_type(8)));
typedef float f32x4 __attribute__((ext_vector_type(4)));
typedef unsigned short u16x4 __attribute__((ext_vector_type(4)));

__device__ __forceinline__ unsigned short f2bf(float f) {
  union { float f; unsigned int u; } v; v.f = f;
  unsigned int u = v.u;
  u += 0x7fffu + ((u >> 16) & 1u);   // round-to-nearest-even
  return (unsigned short)(u >> 16);
}

// ---------------- kernel 1a: rep = silu(g @ ctrl_w^T + ctrl_b), (64x64) ----------------
__global__ void k_rep(const float* __restrict__ grads, const float* __restrict__ ctrl_w,
                      const float* __restrict__ ctrl_b, float* __restrict__ rep_out) {
  int idx = blockIdx.x * 256 + threadIdx.x;   // 0..4095
  int r = idx >> 6, c = idx & 63;
  const float4* g4 = (const float4*)(grads + r * 192);
  const float4* w4 = (const float4*)(ctrl_w + c * 192);
  float acc = ctrl_b[c];
  #pragma unroll 8
  for (int j = 0; j < 48; ++j) {
    float4 a = g4[j], b = w4[j];
    acc += a.x * b.x + a.y * b.y + a.z * b.z + a.w * b.w;
  }
  float sg = 1.0f / (1.0f + expf(-acc));
  rep_out[idx] = acc * sg;   // silu
}

// ---------------- kernel 1b: full q pipeline -> scw (bf16 [k][o][i]) + sbias ----------------
__global__ void k_qpipe(const float* __restrict__ rep, const float* __restrict__ q_ema,
    const float* __restrict__ W, const float* __restrict__ conv_w, const float* __restrict__ conv_b,
    const float* __restrict__ cw_w, const float* __restrict__ cw_b,
    const float* __restrict__ cb_w, const float* __restrict__ cb_b,
    const float* __restrict__ cf_w, const float* __restrict__ cf_b,
    const float* __restrict__ tau_w1, const float* __restrict__ tau_b1,
    const float* __restrict__ tau_w2, const float* __restrict__ tau_b2,
    const int* __restrict__ trigger,
    unsigned short* __restrict__ scw, float* __restrict__ sbias) {
  __shared__ float s_q1[320];
  __shared__ float s_q2[320];
  __shared__ float s_h[64 * 17];
  __shared__ float s_s[64];
  __shared__ float s_part[320];
  __shared__ float s_att[32];
  __shared__ float s_red[4];   // tau, v0, v1, v2
  __shared__ int   s_idx[3];
  int tid = threadIdx.x;       // 0..319

  // ---- q0 (w|b|f) -> q1 = 0.85*q0 + 0.15*q_ema ----
  {
    const float* wrow; float bias; int r;
    if (tid < 192)      { r = tid / 3; int k = tid - r * 3; wrow = cw_w + k * 64; bias = cw_b[k]; }
    else if (tid < 256) { r = tid - 192; wrow = cb_w; bias = cb_b[0]; }
    else                { r = tid - 256; wrow = cf_w; bias = cf_b[0]; }
    float acc = bias;
    const float4* rp = (const float4*)(rep + r * 64);
    const float4* wp = (const float4*)wrow;
    #pragma unroll
    for (int j = 0; j < 16; ++j) {
      float4 a = rp[j], b = wp[j];
      acc += a.x * b.x + a.y * b.y + a.z * b.z + a.w * b.w;
    }
    s_q1[tid] = 0.85f * acc + 0.15f * q_ema[tid];
  }
  // ---- h = silu(rep @ tau_w1^T + tau_b1), (64x16) ----
  for (int e = tid; e < 1024; e += 320) {
    int r = e >> 4, u = e & 15;
    float acc = tau_b1[u];
    const float4* rp = (const float4*)(rep + r * 64);
    const float4* wp = (const float4*)(tau_w1 + u * 64);
    #pragma unroll
    for (int j = 0; j < 16; ++j) {
      float4 a = rp[j], b = wp[j];
      acc += a.x * b.x + a.y * b.y + a.z * b.z + a.w * b.w;
    }
    s_h[r * 17 + u] = acc / (1.0f + expf(-acc));
  }
  __syncthreads();
  // ---- s[r] = sigmoid(h @ tau_w2^T + tau_b2) ----
  if (tid < 64) {
    float acc = tau_b2[0];
    #pragma unroll
    for (int u = 0; u < 16; ++u) acc += s_h[tid * 17 + u] * tau_w2[u];
    s_s[tid] = 1.0f / (1.0f + expf(-acc));
  }
  // ---- att logits partials: q1 @ W / TEMP ----
  {
    int m = tid & 31, pg = tid >> 5;   // pg in 0..9
    float acc = 0.f;
    #pragma unroll
    for (int pp = 0; pp < 32; ++pp) {
      int p = pg * 32 + pp;
      acc += s_q1[p] * W[p * 32 + m];
    }
    s_part[tid] = acc;
  }
  __syncthreads();
  if (tid < 32) {
    float acc = 0.f;
    #pragma unroll
    for (int pg = 0; pg < 10; ++pg) acc += s_part[pg * 32 + tid];
    s_att[tid] = acc * 2.0f;   // /TEMP, TEMP=0.5
  }
  __syncthreads();
  // ---- tau, softmax, top-3 (single thread; 32 values) ----
  if (tid == 0) {
    float tau = 0.f;
    for (int r = 0; r < 64; ++r) tau += s_s[r];
    tau = tau * (1.0f / 64.0f) * 0.5f + 0.5f;
    float mx = s_att[0];
    for (int m = 1; m < 32; ++m) mx = fmaxf(mx, s_att[m]);
    float pr[32]; float sum = 0.f;
    #pragma unroll
    for (int m = 0; m < 32; ++m) { pr[m] = expf(s_att[m] - mx); sum += pr[m]; }
    float inv = 1.0f / sum;
    int i0 = -1, i1 = -1, i2 = -1; float v0 = -1.f, v1 = -1.f, v2 = -1.f;
    #pragma unroll
    for (int m = 0; m < 32; ++m) {
      float v = pr[m];
      if (v > v0)      { v2 = v1; i2 = i1; v1 = v0; i1 = i0; v0 = v; i0 = m; }
      else if (v > v1) { v2 = v1; i2 = i1; v1 = v; i1 = m; }
      else if (v > v2) { v2 = v; i2 = m; }
    }
    s_red[0] = tau; s_red[1] = v0 * inv; s_red[2] = v1 * inv; s_red[3] = v2 * inv;
    s_idx[0] = i0; s_idx[1] = i1; s_idx[2] = i2;
  }
  __syncthreads();
  // ---- q2 = tau*q1 + (1-tau)*old_q (if trigger) ----
  {
    float q1 = s_q1[tid];
    float q2;
    if (trigger[0] == 1) {
      float tau = s_red[0];
      float oq = W[tid * 32 + s_idx[0]] * s_red[1]
               + W[tid * 32 + s_idx[1]] * s_red[2]
               + W[tid * 32 + s_idx[2]] * s_red[3];
      q2 = tau * q1 + (1.0f - tau) * oq;
    } else {
      q2 = q1;
    }
    s_q2[tid] = q2;
  }
  __syncthreads();
  // ---- scw[k][o][i] = conv_w[o][i][k] * wq[o][k] * fq[o]  (bf16) ----
  for (int e = tid; e < 12288; e += 320) {
    int k = e >> 12, rem = e & 4095;
    int o = rem >> 6, i = rem & 63;
    float val = conv_w[(o * 64 + i) * 3 + k] * s_q2[o * 3 + k] * s_q2[256 + o];
    scw[e] = f2bf(val);
  }
  // ---- sbias[o] = fq*conv_b*bq ----
  if (tid < 64) sbias[tid] = s_q2[256 + tid] * conv_b[tid] * s_q2[192 + tid];
}

// ---------------- kernel 2: conv as bf16 MFMA GEMM ----------------
// Block = 256 threads (4 waves); tile: 64 o x 128 t.
// LDS holds x TRANSPOSED: xs[t][i] (130 rows x 72 bf16 pitch) so each MFMA
// B-fragment (8 consecutive i at one t) is a single ds_read_b128 with an
// immediate offset. Wave w owns o-half (w&1) x t-half (w>>1): 12 A-fragments
// in regs (48 VGPR), 8 accumulators, 24 b128 LDS reads, 48 MFMA per thread.
__global__ __launch_bounds__(256, 4) void k_conv(const float* __restrict__ x,
    const unsigned short* __restrict__ scw, const float* __restrict__ sbias,
    float* __restrict__ out) {
  __shared__ __align__(16) unsigned short xs[130 * TP];   // [tr][i], tr = t_local + 1
  __shared__ float sb[64];
  const int tid = threadIdx.x;
  const int b = blockIdx.y;
  const int t0 = blockIdx.x * TT;

  const int lane = tid & 63;
  const int wv   = tid >> 6;
  const int quad = lane >> 4;
  const int l15  = lane & 15;
  const int wm   = wv & 1;          // o-half: o in [wm*32, wm*32+32)
  const int wt   = (wv >> 1) * 64;  // t-offset within tile: [wt, wt+64)

  if (tid < 64) sb[tid] = sbias[tid];

  // A fragments (weights): A[m=l15][c=quad*8+j] per (k, ii, m2). 12 x 16B global loads (L2/L3-hot).
  bf16x8 afr[3][2][2];
  #pragma unroll
  for (int k = 0; k < 3; ++k)
    #pragma unroll
    for (int ii = 0; ii < 2; ++ii)
      #pragma unroll
      for (int m2 = 0; m2 < 2; ++m2)
        afr[k][ii][m2] = *(const bf16x8*)(scw + k * 4096 + (wm * 32 + m2 * 16 + l15) * 64 + ii * 32 + quad * 8);

  // ---- stage x[b, :, t0-1 .. t0+128] transposed into xs[t][i] (bf16) ----
  // Interior: each thread loads 4 adjacent i-rows at one t (coalesced scalar
  // dword loads across lanes), packs to one 8B LDS row-contiguous write.
  const int tl  = tid & 127;   // t within tile, constant across iterations
  const int i4b = tid >> 7;    // 0 or 1
  const float* xb = x + (size_t)b * (64 * 8192);
  {
    const float* xp = xb + t0 + tl;
    #pragma unroll
    for (int it = 0; it < 8; ++it) {
      const int i4 = i4b + it * 2;              // 0..15
      const float* p = xp + (size_t)i4 * 4 * 8192;
      float f0 = p[0];
      float f1 = p[8192];
      float f2 = p[16384];
      float f3 = p[24576];
      u16x4 v;
      v[0] = f2bf(f0); v[1] = f2bf(f1); v[2] = f2bf(f2); v[3] = f2bf(f3);
      *(u16x4*)(xs + (tl + 1) * TP + i4 * 4) = v;
    }
  }
  // Halo columns tr=0 (t0-1) and tr=129 (t0+128), zero-padded at edges.
  if (tid < 32) {
    const int side = tid >> 4;                  // 0: left, 1: right
    const int i4   = tid & 15;
    const int tg   = side ? (t0 + TT) : (t0 - 1);
    const int ok   = (tg >= 0) && (tg < 8192);
    const int tgc  = tg < 0 ? 0 : (tg > 8191 ? 8191 : tg);
    const float* p = xb + (size_t)i4 * 4 * 8192 + tgc;
    u16x4 v;
    v[0] = ok ? f2bf(p[0])     : (unsigned short)0;
    v[1] = ok ? f2bf(p[8192])  : (unsigned short)0;
    v[2] = ok ? f2bf(p[16384]) : (unsigned short)0;
    v[3] = ok ? f2bf(p[24576]) : (unsigned short)0;
    *(u16x4*)(xs + (side ? 129 : 0) * TP + i4 * 4) = v;
  }

  __syncthreads();

  f32x4 acc[2][4];
  #pragma unroll
  for (int m2 = 0; m2 < 2; ++m2)
    #pragma unroll
    for (int n = 0; n < 4; ++n)
      acc[m2][n] = (f32x4){0.f, 0.f, 0.f, 0.f};

  // B[c=quad*8+j][n=l15] = x[i = ii*32+quad*8+j][t = t0 + wt + n*16 + l15 + k - 1]
  //   -> xs row tr = wt + n*16 + l15 + k, cols [ii*32+quad*8 .. +7]: one b128.
  // Per-thread base reg + compile-time immediates for all 24 reads.
  const char* xsb = (const char*)xs + (wt + l15) * (TP * 2) + quad * 16;
  #pragma unroll
  for (int k = 0; k < 3; ++k) {
    #pragma unroll
    for (int ii = 0; ii < 2; ++ii) {
      #pragma unroll
      for (int n = 0; n < 4; ++n) {
        const bf16x8 bfr = *(const bf16x8*)(xsb + k * (TP * 2) + n * (16 * TP * 2) + ii * 64);
        acc[0][n] = __builtin_amdgcn_mfma_f32_16x16x32_bf16(afr[k][ii][0], bfr, acc[0][n], 0, 0, 0);
        acc[1][n] = __builtin_amdgcn_mfma_f32_16x16x32_bf16(afr[k][ii][1], bfr, acc[1][n], 0, 0, 0);
      }
    }
  }

  // epilogue: C/D layout col = l15 (t), row = quad*4 + r (o); stores coalesce
  // to 64B segments per 16-lane group.
  #pragma unroll
  for (int m2 = 0; m2 < 2; ++m2) {
    const int ob = wm * 32 + m2 * 16 + quad * 4;
    #pragma unroll
    for (int n = 0; n < 4; ++n) {
      float* op = out + ((size_t)(b * 64 + ob)) * 8192 + t0 + wt + n * 16 + l15;
      #pragma unroll
      for (int r = 0; r < 4; ++r)
        op[(size_t)r * 8192] = acc[m2][n][r] + sb[ob + r];
    }
  }
}

extern "C" void kernel_launch(void* const* d_in, const int* in_sizes, int n_in,
                              void* d_out, int out_size, void* d_ws, size_t ws_size,
                              hipStream_t stream) {
  const float* x      = (const float*)d_in[0];
  const float* grads  = (const float*)d_in[1];
  const float* q_ema  = (const float*)d_in[2];
  const float* W      = (const float*)d_in[3];
  const float* conv_w = (const float*)d_in[4];
  const float* conv_b = (const float*)d_in[5];
  const float* ctrl_w = (const float*)d_in[6];
  const float* ctrl_b = (const float*)d_in[7];
  const float* cw_w   = (const float*)d_in[8];
  const float* cw_b   = (const float*)d_in[9];
  const float* cb_w   = (const float*)d_in[10];
  const float* cb_b   = (const float*)d_in[11];
  const float* cf_w   = (const float*)d_in[12];
  const float* cf_b   = (const float*)d_in[13];
  const float* tau_w1 = (const float*)d_in[14];
  const float* tau_b1 = (const float*)d_in[15];
  const float* tau_w2 = (const float*)d_in[16];
  const float* tau_b2 = (const float*)d_in[17];
  const int*   trigger = (const int*)d_in[18];
  float* out = (float*)d_out;

  // workspace layout: rep fp32[4096] @0 | scw bf16[12288] @16384 | sbias fp32[64] @40960
  float*          ws_rep   = (float*)d_ws;
  unsigned short* ws_scw   = (unsigned short*)((char*)d_ws + 16384);
  float*          ws_sbias = (float*)((char*)d_ws + 16384 + 24576);

  k_rep<<<16, 256, 0, stream>>>(grads, ctrl_w, ctrl_b, ws_rep);
  k_qpipe<<<1, 320, 0, stream>>>(ws_rep, q_ema, W, conv_w, conv_b, cw_w, cw_b, cb_w, cb_b,
                                 cf_w, cf_b, tau_w1, tau_b1, tau_w2, tau_b2, trigger,
                                 ws_scw, ws_sbias);
  k_conv<<<dim3(64, 64), 256, 0, stream>>>(x, ws_scw, ws_sbias, out);
}